// Round 3
// baseline (408.094 us; speedup 1.0000x reference)
//
#include <hip/hip_runtime.h>
#include <math.h>

#define B_ 64
#define N_ 2048
#define O_ 32
#define I_ 16
#define D_ 32
#define OD_ 1024

typedef __attribute__((ext_vector_type(8))) short bf16x8;
typedef __attribute__((ext_vector_type(4))) float f32x4;

union FragU { unsigned u[4]; uint4 v; bf16x8 f; };

// lgkm-only barrier: does not drain vmcnt (global prefetches stay in flight).
__device__ __forceinline__ void barrier_lds() {
  asm volatile("s_waitcnt lgkmcnt(0)\n\ts_barrier" ::: "memory");
}

// ---- DPP cross-lane (VALU pipe, no LDS traffic) ----
template <int CTRL>
__device__ __forceinline__ float dpp_mov_f(float x) {
  return __int_as_float(
      __builtin_amdgcn_update_dpp(0, __float_as_int(x), CTRL, 0xf, 0xf, true));
}
// all-reduce sum over 16-lane row (dist 8,4 via row_ror; 2,1 via quad_perm)
__device__ __forceinline__ float row16_sum(float x) {
  x += dpp_mov_f<0x128>(x);  // row_ror:8
  x += dpp_mov_f<0x124>(x);  // row_ror:4
  x += dpp_mov_f<0x4e>(x);   // quad_perm [2,3,0,1]
  x += dpp_mov_f<0xb1>(x);   // quad_perm [1,0,3,2]
  return x;
}
__device__ __forceinline__ float grp32_max(float x) {
  x = fmaxf(x, dpp_mov_f<0xb1>(x));
  x = fmaxf(x, dpp_mov_f<0x4e>(x));
  x = fmaxf(x, dpp_mov_f<0x124>(x));
  x = fmaxf(x, dpp_mov_f<0x128>(x));
  x = fmaxf(x, __shfl_xor(x, 16));
  return x;
}
__device__ __forceinline__ float grp32_sum(float x) {
  x += dpp_mov_f<0xb1>(x);
  x += dpp_mov_f<0x4e>(x);
  x += dpp_mov_f<0x124>(x);
  x += dpp_mov_f<0x128>(x);
  x += __shfl_xor(x, 16);
  return x;
}

__device__ __forceinline__ void dk_split(float f, unsigned &h, unsigned &l) {
  unsigned u = __float_as_uint(f);
  h = u & 0xffff0000u;
  float lo = f - __uint_as_float(h);
  l = __float_as_uint(lo) >> 16;
}
__device__ __forceinline__ void dk_split16(float f, unsigned short &h,
                                           unsigned short &l) {
  unsigned u = __float_as_uint(f);
  unsigned hu = u & 0xffff0000u;
  h = (unsigned short)(u >> 16);
  float lo = f - __uint_as_float(hu);
  l = (unsigned short)(__float_as_uint(lo) >> 16);
}
__device__ __forceinline__ unsigned pk(unsigned short e0, unsigned short e1) {
  return (unsigned)e0 | ((unsigned)e1 << 16);
}

// ---- merged prep v3: LDS-transpose + NON-TEMPORAL input loads ----
// W and x are dead after this kernel (packed path). nt loads keep them out of
// L3 so the 134 MB WP stream stays L3-resident for the 3 routing passes.
// blocks [0,8192) pack W -> WP; [8192,8704) pack x -> XP.
// WP u4 idx = (((n*32+o)*2 + dhalf)*4 + sel*2 + qp)*16 + c   (sel0=hi, sel1=lo)
// XP u4 idx = (((bg*2048+n)*2 + sel)*2 + qp)*16 + c ; b = bg*16 + c
__global__ __launch_bounds__(256) void prep_all(const float* __restrict__ W,
                                                const float* __restrict__ x,
                                                uint4* __restrict__ WP,
                                                uint4* __restrict__ XP) {
  __shared__ float tile[8 * 512];  // 16 KB; 8 blocks/CU still fits
  const int tid = threadIdx.x;
  if (blockIdx.x < 8192) {
    const int pair0 = blockIdx.x * 8;  // (n*32+o) linear pair index
    // ---- phase 1: contiguous nt float4 stage of W[pair0 .. pair0+8) ----
    const f32x4* gsrc = (const f32x4*)(W + (size_t)pair0 * 512);
    f32x4* lds4 = (f32x4*)tile;
#pragma unroll
    for (int k = 0; k < 4; ++k)
      lds4[tid + k * 256] = __builtin_nontemporal_load(gsrc + tid + k * 256);
    __syncthreads();
    // ---- phase 2: split+pack one i-column; coalesced uint4 writes ----
    const int p = tid >> 5;        // which pair within block
    const int d = tid & 31;
    const int pair = pair0 + p;    // == n*32 + o
    unsigned short hh[I_], ll[I_];
#pragma unroll
    for (int i = 0; i < I_; ++i)
      dk_split16(tile[p * 512 + i * 32 + d], hh[i], ll[i]);
    const int c = d & 15, dhalf = d >> 4;
    size_t base = ((size_t)pair * 2 + dhalf) * 4;
#pragma unroll
    for (int sel = 0; sel < 2; ++sel) {
      const unsigned short* e = sel ? ll : hh;
#pragma unroll
      for (int qp = 0; qp < 2; ++qp) {
        uint4 u;
        u.x = pk(e[qp * 8 + 0], e[qp * 8 + 1]);
        u.y = pk(e[qp * 8 + 2], e[qp * 8 + 3]);
        u.z = pk(e[qp * 8 + 4], e[qp * 8 + 5]);
        u.w = pk(e[qp * 8 + 6], e[qp * 8 + 7]);
        WP[(base + sel * 2 + qp) * 16 + c] = u;
      }
    }
  } else {
    int t = (blockIdx.x - 8192) * 256 + tid;  // 131,072
    int c = t & 15, n = (t >> 4) & 2047, bg = t >> 15;
    const f32x4* xq = (const f32x4*)(x + ((size_t)(bg * 16 + c) * N_ + n) * I_);
    float xv[I_];
#pragma unroll
    for (int k = 0; k < 4; ++k) {
      f32x4 q4 = __builtin_nontemporal_load(xq + k);
      xv[4 * k + 0] = q4[0];
      xv[4 * k + 1] = q4[1];
      xv[4 * k + 2] = q4[2];
      xv[4 * k + 3] = q4[3];
    }
    unsigned short hh[I_], ll[I_];
#pragma unroll
    for (int i = 0; i < I_; ++i) dk_split16(xv[i], hh[i], ll[i]);
    size_t base = ((size_t)bg * N_ + n) * 4;
#pragma unroll
    for (int sel = 0; sel < 2; ++sel) {
      const unsigned short* e = sel ? ll : hh;
#pragma unroll
      for (int qp = 0; qp < 2; ++qp) {
        uint4 u;
        u.x = pk(e[qp * 8 + 0], e[qp * 8 + 1]);
        u.y = pk(e[qp * 8 + 2], e[qp * 8 + 3]);
        u.z = pk(e[qp * 8 + 4], e[qp * 8 + 5]);
        u.w = pk(e[qp * 8 + 6], e[qp * 8 + 7]);
        XP[(base + sel * 2 + qp) * 16 + c] = u;
      }
    }
  }
}

// ---- fused routing pass v8: NLB=8 superstep batching ----
// v7 had 2 block-wide barriers PER nl (32/pass): 16 waves phase-locked into
// phase1 -> bar -> tiny softmax -> bar -> phase3, 16 times. Barrier skew +
// serial DPP chains dominated (~5x above the VALU floor). v8 batches 8 nl per
// superstep: phase1 x8 (logits -> 32KB LDS, no barriers), bar, softmax for
// 8x32 rows (8 independent DPP chains/thread = real ILP), bar, phase3 x8,
// bar. 7 barriers/pass instead of 33. WP fragment prefetch is a depth-1 ring
// that CROSSES phase boundaries (phase1's last prefetch wraps to phase3's
// first tile; phase3's last feeds next superstep's phase1) so softmax +
// barriers become latency cover. ls_sm is in-place logit->c (each slot owned
// by exactly one phase2 thread). LDS 64 KB, 1 block/CU (grid=256).
template <int UNIFORM>
__global__ __launch_bounds__(1024, 4) void mfma_pass6(
    const uint4* __restrict__ XP, const uint4* __restrict__ WP,
    const float* __restrict__ v, float* __restrict__ partial, int NC) {
  const int tid = threadIdx.x;
  const int lane = tid & 63;
  const int w = tid >> 6;
  const int q = lane >> 4;
  const int c = lane & 15;
  const int qp = q & 1;
  const int ch = blockIdx.x;
  const int bgy = blockIdx.y;  // b in [bgy*32, bgy*32+32)

  __shared__ uint4 xps[2][16][4][16];   // [bgl][nl][rec][c] = 32 KB
  __shared__ float ls_sm[8 * 32 * O_];  // [j][b][o] logits then c = 32 KB

  const int n0 = ch * NC;

  // ---- stage XP (both b-groups, all NC n) into LDS, once ----
  {
    uint4* xf = (uint4*)xps;
    const int total = 2 * NC * 64;
    for (int l = tid; l < total; l += 1024) {
      int bgl = l / (NC * 64);
      int rest = l - bgl * (NC * 64);  // nl*64 + rec*16 + c
      xf[bgl * 1024 + rest] =
          XP[(size_t)(bgy * 2 + bgl) * 131072 + (size_t)n0 * 64 + rest];
    }
  }

  f32x4 s_t[2][4];
#pragma unroll
  for (int bgl = 0; bgl < 2; ++bgl)
#pragma unroll
    for (int ct = 0; ct < 4; ++ct) s_t[bgl][ct] = (f32x4){0.f, 0.f, 0.f, 0.f};

  // hoisted v fragments
  float vreg[2][4][4];
  if (!UNIFORM) {
#pragma unroll
    for (int bgl = 0; bgl < 2; ++bgl)
#pragma unroll
      for (int ct = 0; ct < 4; ++ct) {
        int odc = (2 * w + (ct >> 1)) * 32 + (ct & 1) * 16 + c;
#pragma unroll
        for (int r = 0; r < 4; ++r)
          vreg[bgl][ct][r] =
              v[(size_t)(bgy * 32 + bgl * 16 + q * 4 + r) * OD_ + odc];
      }
  }

  barrier_lds();  // xps ready (compiler inserts vmcnt wait before ds_write)

  // WP u4 idx = n*4096 + o*128 + dh*64 + q*16 + c ; wave's 4 tiles:
  const uint4* wbase = WP + (size_t)(2 * w) * 128 + lane;

  // prologue: tiles for nl=0
  FragU cb[4];
#pragma unroll
  for (int ct = 0; ct < 4; ++ct)
    cb[ct].v = wbase[(size_t)n0 * 4096 + ct * 64];

  if (UNIFORM) {
    for (int nl = 0; nl < NC; ++nl) {
      const size_t n = (size_t)(n0 + nl);
      const size_t np = (nl + 1 < NC) ? n + 1 : n;  // clamp
      FragU cbn[4];
#pragma unroll
      for (int ct = 0; ct < 4; ++ct) cbn[ct].v = wbase[np * 4096 + ct * 64];
#pragma unroll
      for (int bgl = 0; bgl < 2; ++bgl) {
        FragU ah, al;
        ah.v = xps[bgl][nl][qp][c];
        al.v = xps[bgl][nl][2 + qp][c];
#pragma unroll
        for (int ct = 0; ct < 4; ++ct) {
          s_t[bgl][ct] = __builtin_amdgcn_mfma_f32_16x16x32_bf16(
              ah.f, cb[ct].f, s_t[bgl][ct], 0, 0, 0);
          s_t[bgl][ct] = __builtin_amdgcn_mfma_f32_16x16x32_bf16(
              al.f, cb[ct].f, s_t[bgl][ct], 0, 0, 0);
        }
      }
#pragma unroll
      for (int ct = 0; ct < 4; ++ct) cb[ct] = cbn[ct];
    }
  } else {
    // NC must be 16 here (launcher guarantees chunks=128)
    for (int s2 = 0; s2 < 2; ++s2) {
      const int nb = s2 * 8;
      // ---- phase 1: logits for 8 nl, no internal barriers ----
#pragma unroll 2
      for (int j = 0; j < 8; ++j) {
        const int nl = nb + j;
        const size_t n = (size_t)(n0 + nl);
        // prefetch next nl; on last j wrap to this superstep's first nl
        // (phase3 re-reads it after the softmax barriers = long cover)
        const size_t np = (j < 7) ? n + 1 : (size_t)(n0 + nb);
        FragU cbn[4];
#pragma unroll
        for (int ct = 0; ct < 4; ++ct) cbn[ct].v = wbase[np * 4096 + ct * 64];
#pragma unroll
        for (int bgl = 0; bgl < 2; ++bgl) {
          FragU ah, al;
          ah.v = xps[bgl][nl][qp][c];
          al.v = xps[bgl][nl][2 + qp][c];
          float lg[2][4];
#pragma unroll
          for (int ol = 0; ol < 2; ++ol)
#pragma unroll
            for (int r = 0; r < 4; ++r) lg[ol][r] = 0.f;
#pragma unroll
          for (int ct = 0; ct < 4; ++ct) {
            f32x4 acc = (f32x4){0.f, 0.f, 0.f, 0.f};
            acc = __builtin_amdgcn_mfma_f32_16x16x32_bf16(ah.f, cb[ct].f, acc, 0, 0, 0);
            f32x4 u = __builtin_amdgcn_mfma_f32_16x16x32_bf16(al.f, cb[ct].f, acc, 0, 0, 0);
            int ol = ct >> 1;
#pragma unroll
            for (int r = 0; r < 4; ++r)
              lg[ol][r] = fmaf(u[r], vreg[bgl][ct][r], lg[ol][r]);
          }
#pragma unroll
          for (int ol = 0; ol < 2; ++ol)
#pragma unroll
            for (int r = 0; r < 4; ++r) lg[ol][r] = row16_sum(lg[ol][r]);
          if (c == 0) {
#pragma unroll
            for (int ol = 0; ol < 2; ++ol)
#pragma unroll
              for (int r = 0; r < 4; ++r)
                ls_sm[j * 1024 + (bgl * 16 + q * 4 + r) * O_ + 2 * w + ol] =
                    lg[ol][r];
          }
        }
#pragma unroll
        for (int ct = 0; ct < 4; ++ct) cb[ct] = cbn[ct];
      }
      barrier_lds();
      // ---- phase 2: softmax, 8 rows/thread in 2 ILP groups of 4 ----
#pragma unroll
      for (int g = 0; g < 2; ++g) {
        float l[4], mx[4], e[4], sm[4];
#pragma unroll
        for (int jj = 0; jj < 4; ++jj) l[jj] = ls_sm[(g * 4 + jj) * 1024 + tid];
#pragma unroll
        for (int jj = 0; jj < 4; ++jj) mx[jj] = grp32_max(l[jj]);
#pragma unroll
        for (int jj = 0; jj < 4; ++jj) e[jj] = __expf(l[jj] - mx[jj]);
#pragma unroll
        for (int jj = 0; jj < 4; ++jj) sm[jj] = grp32_sum(e[jj]);
#pragma unroll
        for (int jj = 0; jj < 4; ++jj)
          ls_sm[(g * 4 + jj) * 1024 + tid] = e[jj] / sm[jj];
      }
      barrier_lds();
      // ---- phase 3: recompute u_hat, s += c*u, for 8 nl ----
#pragma unroll 2
      for (int j = 0; j < 8; ++j) {
        const int nl = nb + j;
        const size_t n = (size_t)(n0 + nl);
        // prefetch next nl; on last j feed next superstep's phase1 (clamp at
        // the very end)
        const size_t np = (j < 7) ? n + 1
                                  : (s2 == 0 ? (size_t)(n0 + 8) : n);
        FragU cbn[4];
#pragma unroll
        for (int ct = 0; ct < 4; ++ct) cbn[ct].v = wbase[np * 4096 + ct * 64];
#pragma unroll
        for (int bgl = 0; bgl < 2; ++bgl) {
          FragU ah, al;
          ah.v = xps[bgl][nl][qp][c];
          al.v = xps[bgl][nl][2 + qp][c];
#pragma unroll
          for (int ct = 0; ct < 4; ++ct) {
            f32x4 acc = (f32x4){0.f, 0.f, 0.f, 0.f};
            acc = __builtin_amdgcn_mfma_f32_16x16x32_bf16(ah.f, cb[ct].f, acc, 0, 0, 0);
            f32x4 u = __builtin_amdgcn_mfma_f32_16x16x32_bf16(al.f, cb[ct].f, acc, 0, 0, 0);
            int o = 2 * w + (ct >> 1);
#pragma unroll
            for (int r = 0; r < 4; ++r) {
              float cc = ls_sm[j * 1024 + (bgl * 16 + q * 4 + r) * O_ + o];
              s_t[bgl][ct][r] = fmaf(cc, u[r], s_t[bgl][ct][r]);
            }
          }
        }
#pragma unroll
        for (int ct = 0; ct < 4; ++ct) cb[ct] = cbn[ct];
      }
      // protect ls_sm against next superstep's phase1 overwrites
      barrier_lds();
    }
  }

  const float scale = UNIFORM ? (1.f / 32.f) : 1.f;
#pragma unroll
  for (int bgl = 0; bgl < 2; ++bgl)
#pragma unroll
    for (int ct = 0; ct < 4; ++ct) {
      int odc = (2 * w + (ct >> 1)) * 32 + (ct & 1) * 16 + c;
#pragma unroll
      for (int r = 0; r < 4; ++r) {
        partial[((size_t)ch * B_ + bgy * 32 + bgl * 16 + q * 4 + r) * OD_ + odc] =
            s_t[bgl][ct][r] * scale;
      }
    }
}

// ---- fallback (round-2 path, used only if ws too small for WP/XP) ----
template <int UNIFORM>
__global__ __launch_bounds__(512, 4) void mfma_pass_fb(
    const float* __restrict__ x, const float* __restrict__ W,
    const float* __restrict__ v, float* __restrict__ partial, int NC) {
  const int tid = threadIdx.x;
  const int lane = tid & 63;
  const int cg = tid >> 6;
  const int q = lane >> 4;
  const int c = lane & 15;
  const int ch = blockIdx.x;
  const int bg = blockIdx.y;

  __shared__ float ls_logit[16 * O_];
  __shared__ float ls_c[16 * O_];

  f32x4 s_t[8];
#pragma unroll
  for (int ct = 0; ct < 8; ++ct) s_t[ct] = (f32x4){0.f, 0.f, 0.f, 0.f};

  const int n0 = ch * NC;
  const int ih = (q & 1) * 8;
  const float* xrow = x + ((size_t)(bg * 16 + c) * N_) * I_ + ih;

  for (int nl = 0; nl < NC; ++nl) {
    const int n = n0 + nl;
    const float* xp = xrow + (size_t)n * I_;
    float4 xv0 = *(const float4*)xp;
    float4 xv1 = *(const float4*)(xp + 4);
    float xv[8] = {xv0.x, xv0.y, xv0.z, xv0.w, xv1.x, xv1.y, xv1.z, xv1.w};
    FragU a1;
#pragma unroll
    for (int p = 0; p < 4; ++p) {
      unsigned h0, l0, h1, l1;
      dk_split(xv[2 * p], h0, l0);
      dk_split(xv[2 * p + 1], h1, l1);
      a1.u[p] = (q < 2) ? ((h0 >> 16) | h1) : (l0 | (l1 << 16));
    }
    f32x4 u_t[8];
#pragma unroll
    for (int ct = 0; ct < 8; ++ct) {
      const int o = cg * 4 + (ct >> 1);
      const int d = (ct & 1) * 16 + c;
      const float* wp = W + (((size_t)n * O_ + o) * I_ + ih) * D_ + d;
      FragU b1, b2;
#pragma unroll
      for (int p = 0; p < 4; ++p) {
        unsigned h0, l0, h1, l1;
        dk_split(wp[(2 * p) * D_], h0, l0);
        dk_split(wp[(2 * p + 1) * D_], h1, l1);
        b1.u[p] = (h0 >> 16) | h1;
        b2.u[p] = l0 | (l1 << 16);
      }
      if (UNIFORM) {
        s_t[ct] = __builtin_amdgcn_mfma_f32_16x16x32_bf16(a1.f, b1.f, s_t[ct], 0, 0, 0);
        s_t[ct] = __builtin_amdgcn_mfma_f32_16x16x32_bf16(a1.f, b2.f, s_t[ct], 0, 0, 0);
      } else {
        f32x4 acc = (f32x4){0.f, 0.f, 0.f, 0.f};
        acc = __builtin_amdgcn_mfma_f32_16x16x32_bf16(a1.f, b1.f, acc, 0, 0, 0);
        u_t[ct] = __builtin_amdgcn_mfma_f32_16x16x32_bf16(a1.f, b2.f, acc, 0, 0, 0);
      }
    }
    if (!UNIFORM) {
#pragma unroll
      for (int ol = 0; ol < 4; ++ol) {
        float lg[4] = {0.f, 0.f, 0.f, 0.f};
#pragma unroll
        for (int hf = 0; hf < 2; ++hf) {
          int ct = ol * 2 + hf;
          int odc = cg * 128 + ct * 16 + c;
#pragma unroll
          for (int r = 0; r < 4; ++r)
            lg[r] = fmaf(u_t[ct][r], v[(size_t)(bg * 16 + q * 4 + r) * OD_ + odc], lg[r]);
        }
#pragma unroll
        for (int r = 0; r < 4; ++r) {
#pragma unroll
          for (int m = 1; m < 16; m <<= 1) lg[r] += __shfl_xor(lg[r], m);
        }
        if (c == 0) {
#pragma unroll
          for (int r = 0; r < 4; ++r)
            ls_logit[(q * 4 + r) * O_ + cg * 4 + ol] = lg[r];
        }
      }
      __syncthreads();
      {
        int b_l = tid >> 5, o = tid & 31;
        float l = ls_logit[b_l * O_ + o];
        float mx = l;
#pragma unroll
        for (int m = 16; m >= 1; m >>= 1) mx = fmaxf(mx, __shfl_xor(mx, m));
        float e = __expf(l - mx);
        float sm = e;
#pragma unroll
        for (int m = 16; m >= 1; m >>= 1) sm += __shfl_xor(sm, m);
        ls_c[b_l * O_ + o] = e / sm;
      }
      __syncthreads();
#pragma unroll
      for (int ol = 0; ol < 4; ++ol) {
        int o = cg * 4 + ol;
        float cc[4];
#pragma unroll
        for (int r = 0; r < 4; ++r) cc[r] = ls_c[(q * 4 + r) * O_ + o];
#pragma unroll
        for (int hf = 0; hf < 2; ++hf) {
          int ct = ol * 2 + hf;
#pragma unroll
          for (int r = 0; r < 4; ++r)
            s_t[ct][r] = fmaf(cc[r], u_t[ct][r], s_t[ct][r]);
        }
      }
    }
  }

  const float scale = UNIFORM ? (1.f / 32.f) : 1.f;
#pragma unroll
  for (int ct = 0; ct < 8; ++ct) {
#pragma unroll
    for (int r = 0; r < 4; ++r) {
      partial[((size_t)ch * B_ + bg * 16 + q * 4 + r) * OD_ + cg * 128 + ct * 16 + c] =
          s_t[ct][r] * scale;
    }
  }
}

// ---- fused reduce: sum all chunks + squash + optional prev, one kernel ----
// 256 blocks x 256 threads; 4 chunk-slices per block combined via LDS.
__global__ __launch_bounds__(256) void reduce_fused(
    const float4* __restrict__ part, int cq4, const float4* __restrict__ prev,
    float4* __restrict__ out) {
  __shared__ float4 accs[4][64];
  const int lane = threadIdx.x & 63;
  const int cg = threadIdx.x >> 6;
  const int g4 = blockIdx.x * 64 + lane;  // 256*64 = 16384 outputs
  float4 s = make_float4(0.f, 0.f, 0.f, 0.f);
  const int c0 = cg * cq4;
  for (int i = 0; i < cq4; ++i) {
    float4 p = part[(size_t)(c0 + i) * 16384 + g4];
    s.x += p.x; s.y += p.y; s.z += p.z; s.w += p.w;
  }
  accs[cg][lane] = s;
  __syncthreads();
  if (cg == 0) {
    float4 a1 = accs[1][lane], a2 = accs[2][lane], a3 = accs[3][lane];
    s.x += a1.x + a2.x + a3.x;
    s.y += a1.y + a2.y + a3.y;
    s.z += a1.z + a2.z + a3.z;
    s.w += a1.w + a2.w + a3.w;
    float sq = s.x * s.x + s.y * s.y + s.z * s.z + s.w * s.w;
#pragma unroll
    for (int m = 4; m >= 1; m >>= 1) sq += __shfl_xor(sq, m, 8);
    float scale = sq / ((1.f + sq) * (sqrtf(sq) + 1e-6f));
    float4 r = make_float4(s.x * scale, s.y * scale, s.z * scale, s.w * scale);
    if (prev) {
      float4 p = prev[g4];
      r.x += p.x; r.y += p.y; r.z += p.z; r.w += p.w;
    }
    out[g4] = r;
  }
}

// single-stage reduce (fallback path)
__global__ __launch_bounds__(256) void reduce_squash(
    const float4* __restrict__ part, int chunks,
    const float4* __restrict__ prev, float4* __restrict__ out) {
  int g4 = blockIdx.x * 256 + threadIdx.x;
  float4 s = make_float4(0.f, 0.f, 0.f, 0.f);
#pragma unroll 4
  for (int ch = 0; ch < chunks; ++ch) {
    float4 p = part[(size_t)ch * 16384 + g4];
    s.x += p.x; s.y += p.y; s.z += p.z; s.w += p.w;
  }
  float sq = s.x * s.x + s.y * s.y + s.z * s.z + s.w * s.w;
#pragma unroll
  for (int m = 4; m >= 1; m >>= 1) sq += __shfl_xor(sq, m, 8);
  float scale = sq / ((1.f + sq) * (sqrtf(sq) + 1e-6f));
  float4 r = make_float4(s.x * scale, s.y * scale, s.z * scale, s.w * scale);
  if (prev) {
    float4 p = prev[g4];
    r.x += p.x; r.y += p.y; r.z += p.z; r.w += p.w;
  }
  out[g4] = r;
}

extern "C" void kernel_launch(void* const* d_in, const int* in_sizes, int n_in,
                              void* d_out, int out_size, void* d_ws,
                              size_t ws_size, hipStream_t stream) {
  const float* x = (const float*)d_in[0];
  const float* W = (const float*)d_in[1];
  float* out = (float*)d_out;

  const size_t XP_FLOATS = 4ull * 2048 * 4 * 16 * 4;       // 2,097,152
  const size_t WP_FLOATS = 2048ull * 32 * 2 * 4 * 16 * 4;  // 33,554,432

  float* v1 = (float*)d_ws;
  float* vsum = v1 + 65536;
  float* partial = vsum + 65536;

  const int chunks = 128;  // mfma_pass6 requires NC==16
  bool packed_path =
      (131072 + (size_t)chunks * 65536 + XP_FLOATS + WP_FLOATS) * 4 <= ws_size;

  if (packed_path) {
    uint4* XP = (uint4*)(partial + (size_t)chunks * 65536);
    uint4* WP = XP + XP_FLOATS / 4;
    const int NC = N_ / chunks;  // 16
    const int cq4 = chunks / 4;  // 32
    dim3 grid(chunks, 2);

    prep_all<<<8704, 256, 0, stream>>>(W, x, WP, XP);

    mfma_pass6<1><<<grid, 1024, 0, stream>>>(XP, WP, nullptr, partial, NC);
    reduce_fused<<<256, 256, 0, stream>>>((const float4*)partial, cq4, nullptr,
                                          (float4*)v1);
    mfma_pass6<0><<<grid, 1024, 0, stream>>>(XP, WP, v1, partial, NC);
    reduce_fused<<<256, 256, 0, stream>>>((const float4*)partial, cq4,
                                          (const float4*)v1, (float4*)vsum);
    mfma_pass6<0><<<grid, 1024, 0, stream>>>(XP, WP, vsum, partial, NC);
    reduce_fused<<<256, 256, 0, stream>>>((const float4*)partial, cq4, nullptr,
                                          (float4*)out);
  } else {
    int fchunks = 128;
    while (fchunks > 1 && (131072 + (size_t)fchunks * 65536) * 4 > ws_size)
      fchunks >>= 1;
    int NC = N_ / fchunks;
    dim3 grid(fchunks, 4);

    mfma_pass_fb<1><<<grid, 512, 0, stream>>>(x, W, nullptr, partial, NC);
    reduce_squash<<<64, 256, 0, stream>>>((const float4*)partial, fchunks,
                                          nullptr, (float4*)v1);
    mfma_pass_fb<0><<<grid, 512, 0, stream>>>(x, W, v1, partial, NC);
    reduce_squash<<<64, 256, 0, stream>>>((const float4*)partial, fchunks,
                                          (const float4*)v1, (float4*)vsum);
    mfma_pass_fb<0><<<grid, 512, 0, stream>>>(x, W, vsum, partial, NC);
    reduce_squash<<<64, 256, 0, stream>>>((const float4*)partial, fchunks,
                                          nullptr, (float4*)out);
  }
}

// Round 4
// 348.074 us; speedup vs baseline: 1.1724x; 1.1724x over previous
//
#include <hip/hip_runtime.h>
#include <math.h>

#define B_ 64
#define N_ 2048
#define O_ 32
#define I_ 16
#define D_ 32
#define OD_ 1024

typedef __attribute__((ext_vector_type(8))) short bf16x8;
typedef __attribute__((ext_vector_type(4))) float f32x4;

union FragU { unsigned u[4]; uint4 v; bf16x8 f; };

// lgkm-only barrier: does not drain vmcnt (global prefetches stay in flight).
__device__ __forceinline__ void barrier_lds() {
  asm volatile("s_waitcnt lgkmcnt(0)\n\ts_barrier" ::: "memory");
}

// ---- DPP cross-lane (VALU pipe, no LDS traffic) ----
template <int CTRL>
__device__ __forceinline__ float dpp_mov_f(float x) {
  return __int_as_float(
      __builtin_amdgcn_update_dpp(0, __float_as_int(x), CTRL, 0xf, 0xf, true));
}
__device__ __forceinline__ float grp32_max(float x) {
  x = fmaxf(x, dpp_mov_f<0xb1>(x));
  x = fmaxf(x, dpp_mov_f<0x4e>(x));
  x = fmaxf(x, dpp_mov_f<0x124>(x));
  x = fmaxf(x, dpp_mov_f<0x128>(x));
  x = fmaxf(x, __shfl_xor(x, 16));
  return x;
}
__device__ __forceinline__ float grp32_sum(float x) {
  x += dpp_mov_f<0xb1>(x);
  x += dpp_mov_f<0x4e>(x);
  x += dpp_mov_f<0x124>(x);
  x += dpp_mov_f<0x128>(x);
  x += __shfl_xor(x, 16);
  return x;
}

__device__ __forceinline__ void dk_split(float f, unsigned &h, unsigned &l) {
  unsigned u = __float_as_uint(f);
  h = u & 0xffff0000u;
  float lo = f - __uint_as_float(h);
  l = __float_as_uint(lo) >> 16;
}
__device__ __forceinline__ void dk_split16(float f, unsigned short &h,
                                           unsigned short &l) {
  unsigned u = __float_as_uint(f);
  unsigned hu = u & 0xffff0000u;
  h = (unsigned short)(u >> 16);
  float lo = f - __uint_as_float(hu);
  l = (unsigned short)(__float_as_uint(lo) >> 16);
}
__device__ __forceinline__ unsigned pk(unsigned short e0, unsigned short e1) {
  return (unsigned)e0 | ((unsigned)e1 << 16);
}

// ---- merged prep v3: LDS-transpose + NON-TEMPORAL input loads ----
// W and x are dead after this kernel (packed path). nt loads keep them out of
// L3 so the 134 MB WP stream stays L3-resident for the 3 routing passes.
// blocks [0,8192) pack W -> WP; [8192,8704) pack x -> XP.
// WP u4 idx = (((n*32+o)*2 + dhalf)*4 + sel*2 + qp)*16 + c   (sel0=hi, sel1=lo)
// XP u4 idx = (((bg*2048+n)*2 + sel)*2 + qp)*16 + c ; b = bg*16 + c
__global__ __launch_bounds__(256) void prep_all(const float* __restrict__ W,
                                                const float* __restrict__ x,
                                                uint4* __restrict__ WP,
                                                uint4* __restrict__ XP) {
  __shared__ float tile[8 * 512];  // 16 KB; 8 blocks/CU still fits
  const int tid = threadIdx.x;
  if (blockIdx.x < 8192) {
    const int pair0 = blockIdx.x * 8;  // (n*32+o) linear pair index
    // ---- phase 1: contiguous nt float4 stage of W[pair0 .. pair0+8) ----
    const f32x4* gsrc = (const f32x4*)(W + (size_t)pair0 * 512);
    f32x4* lds4 = (f32x4*)tile;
#pragma unroll
    for (int k = 0; k < 4; ++k)
      lds4[tid + k * 256] = __builtin_nontemporal_load(gsrc + tid + k * 256);
    __syncthreads();
    // ---- phase 2: split+pack one i-column; coalesced uint4 writes ----
    const int p = tid >> 5;        // which pair within block
    const int d = tid & 31;
    const int pair = pair0 + p;    // == n*32 + o
    unsigned short hh[I_], ll[I_];
#pragma unroll
    for (int i = 0; i < I_; ++i)
      dk_split16(tile[p * 512 + i * 32 + d], hh[i], ll[i]);
    const int c = d & 15, dhalf = d >> 4;
    size_t base = ((size_t)pair * 2 + dhalf) * 4;
#pragma unroll
    for (int sel = 0; sel < 2; ++sel) {
      const unsigned short* e = sel ? ll : hh;
#pragma unroll
      for (int qp = 0; qp < 2; ++qp) {
        uint4 u;
        u.x = pk(e[qp * 8 + 0], e[qp * 8 + 1]);
        u.y = pk(e[qp * 8 + 2], e[qp * 8 + 3]);
        u.z = pk(e[qp * 8 + 4], e[qp * 8 + 5]);
        u.w = pk(e[qp * 8 + 6], e[qp * 8 + 7]);
        WP[(base + sel * 2 + qp) * 16 + c] = u;
      }
    }
  } else {
    int t = (blockIdx.x - 8192) * 256 + tid;  // 131,072
    int c = t & 15, n = (t >> 4) & 2047, bg = t >> 15;
    const f32x4* xq = (const f32x4*)(x + ((size_t)(bg * 16 + c) * N_ + n) * I_);
    float xv[I_];
#pragma unroll
    for (int k = 0; k < 4; ++k) {
      f32x4 q4 = __builtin_nontemporal_load(xq + k);
      xv[4 * k + 0] = q4[0];
      xv[4 * k + 1] = q4[1];
      xv[4 * k + 2] = q4[2];
      xv[4 * k + 3] = q4[3];
    }
    unsigned short hh[I_], ll[I_];
#pragma unroll
    for (int i = 0; i < I_; ++i) dk_split16(xv[i], hh[i], ll[i]);
    size_t base = ((size_t)bg * N_ + n) * 4;
#pragma unroll
    for (int sel = 0; sel < 2; ++sel) {
      const unsigned short* e = sel ? ll : hh;
#pragma unroll
      for (int qp = 0; qp < 2; ++qp) {
        uint4 u;
        u.x = pk(e[qp * 8 + 0], e[qp * 8 + 1]);
        u.y = pk(e[qp * 8 + 2], e[qp * 8 + 3]);
        u.z = pk(e[qp * 8 + 4], e[qp * 8 + 5]);
        u.w = pk(e[qp * 8 + 6], e[qp * 8 + 7]);
        XP[(base + sel * 2 + qp) * 16 + c] = u;
      }
    }
  }
}

// ---- fused routing pass v9: v7 structure + TRANSPOSED logit MFMA ----
// v8's superstep re-loaded WP in phase3 (regression; FETCH showed the re-read
// bounced off L3). v9 reverts to v7's single-load 2-barrier/nl skeleton and
// attacks the measured VALU floor instead: the logit dot u.v over d spanned
// 16 c-lanes, costing ~128 dependent DPP ops/thread/nl. Since MFMA A/B
// fragments share the same lane layout, mfma(cb, ah) yields uT[d][b] from the
// SAME registers (hi/lo split-double k-slices pair identically). With uT each
// thread holds 8 d-values for ONE b (col=c): logit = 8 in-thread fmaf +
// shfl_xor(16) + shfl_xor(32) over the 4 q-groups. ~95 VALU/thread/nl
// removed. Phase3 keeps the normal orientation (s_t layout unchanged).
// Logit/c LDS is [o][b] padded to 33 (conflict-free write c-stride-1, read
// stride-33). Softmax math unchanged.
template <int UNIFORM>
__global__ __launch_bounds__(1024, 4) void mfma_pass6(
    const uint4* __restrict__ XP, const uint4* __restrict__ WP,
    const float* __restrict__ v, float* __restrict__ partial, int NC) {
  const int tid = threadIdx.x;
  const int lane = tid & 63;
  const int w = tid >> 6;
  const int q = lane >> 4;
  const int c = lane & 15;
  const int qp = q & 1;
  const int ch = blockIdx.x;
  const int bgy = blockIdx.y;  // b in [bgy*32, bgy*32+32)

  __shared__ uint4 xps[2][16][4][16];  // [bgl][nl][rec][c] = 32 KB
  __shared__ float ls_l[32 * 33];      // logits [o][b] pad 33
  __shared__ float ls_c2[32 * 33];     // c      [o][b] pad 33

  const int n0 = ch * NC;

  // ---- stage XP (both b-groups, all NC n) into LDS, once ----
  {
    uint4* xf = (uint4*)xps;
    const int total = 2 * NC * 64;
    for (int l = tid; l < total; l += 1024) {
      int bgl = l / (NC * 64);
      int rest = l - bgl * (NC * 64);  // nl*64 + rec*16 + c
      xf[bgl * 1024 + rest] =
          XP[(size_t)(bgy * 2 + bgl) * 131072 + (size_t)n0 * 64 + rest];
    }
  }

  f32x4 s_t[2][4];
#pragma unroll
  for (int bgl = 0; bgl < 2; ++bgl)
#pragma unroll
    for (int ct = 0; ct < 4; ++ct) s_t[bgl][ct] = (f32x4){0.f, 0.f, 0.f, 0.f};

  // hoisted v fragments, indexed for the TRANSPOSED u: b=col=c, d=q*4+r
  float vreg[2][4][4];
  if (!UNIFORM) {
#pragma unroll
    for (int bgl = 0; bgl < 2; ++bgl)
#pragma unroll
      for (int ct = 0; ct < 4; ++ct) {
        const float4 vv = *(const float4*)&v[(size_t)(bgy * 32 + bgl * 16 + c) * OD_ +
                                             (2 * w + (ct >> 1)) * 32 +
                                             (ct & 1) * 16 + q * 4];
        vreg[bgl][ct][0] = vv.x;
        vreg[bgl][ct][1] = vv.y;
        vreg[bgl][ct][2] = vv.z;
        vreg[bgl][ct][3] = vv.w;
      }
  }

  barrier_lds();  // xps ready (compiler inserts vmcnt wait before ds_write)

  // WP u4 idx = n*4096 + o*128 + dh*64 + q*16 + c ; wave's 4 tiles:
  const uint4* wbase = WP + (size_t)(2 * w) * 128 + lane;

  // prologue: tiles for nl=0
  FragU cb[4];
#pragma unroll
  for (int ct = 0; ct < 4; ++ct)
    cb[ct].v = wbase[(size_t)n0 * 4096 + ct * 64];

  if (UNIFORM) {
    for (int nl = 0; nl < NC; ++nl) {
      const size_t n = (size_t)(n0 + nl);
      const size_t np = (nl + 1 < NC) ? n + 1 : n;  // clamp
      FragU cbn[4];
#pragma unroll
      for (int ct = 0; ct < 4; ++ct) cbn[ct].v = wbase[np * 4096 + ct * 64];
#pragma unroll
      for (int bgl = 0; bgl < 2; ++bgl) {
        FragU ah, al;
        ah.v = xps[bgl][nl][qp][c];
        al.v = xps[bgl][nl][2 + qp][c];
#pragma unroll
        for (int ct = 0; ct < 4; ++ct) {
          s_t[bgl][ct] = __builtin_amdgcn_mfma_f32_16x16x32_bf16(
              ah.f, cb[ct].f, s_t[bgl][ct], 0, 0, 0);
          s_t[bgl][ct] = __builtin_amdgcn_mfma_f32_16x16x32_bf16(
              al.f, cb[ct].f, s_t[bgl][ct], 0, 0, 0);
        }
      }
#pragma unroll
      for (int ct = 0; ct < 4; ++ct) cb[ct] = cbn[ct];
    }
  } else {
    for (int nl = 0; nl < NC; ++nl) {
      const size_t n = (size_t)(n0 + nl);
      const size_t np = (nl + 1 < NC) ? n + 1 : n;  // clamp

      // ---- phase 1 (transposed): uT[d][b] -> logits, no cross-lane dot ----
#pragma unroll
      for (int bgl = 0; bgl < 2; ++bgl) {
        FragU ah, al;
        ah.v = xps[bgl][nl][qp][c];
        al.v = xps[bgl][nl][2 + qp][c];
        float lgol[2] = {0.f, 0.f};
#pragma unroll
        for (int ct = 0; ct < 4; ++ct) {
          f32x4 accT = (f32x4){0.f, 0.f, 0.f, 0.f};
          accT = __builtin_amdgcn_mfma_f32_16x16x32_bf16(cb[ct].f, ah.f, accT, 0, 0, 0);
          f32x4 uT = __builtin_amdgcn_mfma_f32_16x16x32_bf16(cb[ct].f, al.f, accT, 0, 0, 0);
          const int ol = ct >> 1;
#pragma unroll
          for (int r = 0; r < 4; ++r)
            lgol[ol] = fmaf(uT[r], vreg[bgl][ct][r], lgol[ol]);
        }
        // reduce over the 4 q-groups (d-slices) at fixed c
#pragma unroll
        for (int ol = 0; ol < 2; ++ol) {
          float t = lgol[ol];
          t += __shfl_xor(t, 16);
          t += __shfl_xor(t, 32);
          if (q == 0) ls_l[(2 * w + ol) * 33 + bgl * 16 + c] = t;
        }
      }
      // ---- prefetch next WP tiles: latency spans softmax+barriers+phase3
      FragU cbn[4];
#pragma unroll
      for (int ct = 0; ct < 4; ++ct) cbn[ct].v = wbase[np * 4096 + ct * 64];

      barrier_lds();
      // ---- phase 2: softmax, 1024 rows = 1024 threads (o=tid&31, b=tid>>5)
      {
        const int idx = (tid & 31) * 33 + (tid >> 5);
        float l = ls_l[idx];
        float mx = grp32_max(l);
        float e = __expf(l - mx);
        float sm = grp32_sum(e);
        ls_c2[idx] = e / sm;
      }
      barrier_lds();
      // ---- phase 3 (normal orientation): recompute u_hat, s += c*u ----
#pragma unroll
      for (int bgl = 0; bgl < 2; ++bgl) {
        FragU ah, al;
        ah.v = xps[bgl][nl][qp][c];
        al.v = xps[bgl][nl][2 + qp][c];
#pragma unroll
        for (int ct = 0; ct < 4; ++ct) {
          f32x4 acc = (f32x4){0.f, 0.f, 0.f, 0.f};
          acc = __builtin_amdgcn_mfma_f32_16x16x32_bf16(ah.f, cb[ct].f, acc, 0, 0, 0);
          f32x4 u = __builtin_amdgcn_mfma_f32_16x16x32_bf16(al.f, cb[ct].f, acc, 0, 0, 0);
          const int o = 2 * w + (ct >> 1);
#pragma unroll
          for (int r = 0; r < 4; ++r) {
            float cc = ls_c2[o * 33 + bgl * 16 + q * 4 + r];
            s_t[bgl][ct][r] = fmaf(cc, u[r], s_t[bgl][ct][r]);
          }
        }
      }
      // rotate: vmcnt wait for cbn lands here, after a full nl of cover
#pragma unroll
      for (int ct = 0; ct < 4; ++ct) cb[ct] = cbn[ct];
    }
  }

  const float scale = UNIFORM ? (1.f / 32.f) : 1.f;
#pragma unroll
  for (int bgl = 0; bgl < 2; ++bgl)
#pragma unroll
    for (int ct = 0; ct < 4; ++ct) {
      int odc = (2 * w + (ct >> 1)) * 32 + (ct & 1) * 16 + c;
#pragma unroll
      for (int r = 0; r < 4; ++r) {
        partial[((size_t)ch * B_ + bgy * 32 + bgl * 16 + q * 4 + r) * OD_ + odc] =
            s_t[bgl][ct][r] * scale;
      }
    }
}

// ---- fallback (round-2 path, used only if ws too small for WP/XP) ----
template <int UNIFORM>
__global__ __launch_bounds__(512, 4) void mfma_pass_fb(
    const float* __restrict__ x, const float* __restrict__ W,
    const float* __restrict__ v, float* __restrict__ partial, int NC) {
  const int tid = threadIdx.x;
  const int lane = tid & 63;
  const int cg = tid >> 6;
  const int q = lane >> 4;
  const int c = lane & 15;
  const int ch = blockIdx.x;
  const int bg = blockIdx.y;

  __shared__ float ls_logit[16 * O_];
  __shared__ float ls_c[16 * O_];

  f32x4 s_t[8];
#pragma unroll
  for (int ct = 0; ct < 8; ++ct) s_t[ct] = (f32x4){0.f, 0.f, 0.f, 0.f};

  const int n0 = ch * NC;
  const int ih = (q & 1) * 8;
  const float* xrow = x + ((size_t)(bg * 16 + c) * N_) * I_ + ih;

  for (int nl = 0; nl < NC; ++nl) {
    const int n = n0 + nl;
    const float* xp = xrow + (size_t)n * I_;
    float4 xv0 = *(const float4*)xp;
    float4 xv1 = *(const float4*)(xp + 4);
    float xv[8] = {xv0.x, xv0.y, xv0.z, xv0.w, xv1.x, xv1.y, xv1.z, xv1.w};
    FragU a1;
#pragma unroll
    for (int p = 0; p < 4; ++p) {
      unsigned h0, l0, h1, l1;
      dk_split(xv[2 * p], h0, l0);
      dk_split(xv[2 * p + 1], h1, l1);
      a1.u[p] = (q < 2) ? ((h0 >> 16) | h1) : (l0 | (l1 << 16));
    }
    f32x4 u_t[8];
#pragma unroll
    for (int ct = 0; ct < 8; ++ct) {
      const int o = cg * 4 + (ct >> 1);
      const int d = (ct & 1) * 16 + c;
      const float* wp = W + (((size_t)n * O_ + o) * I_ + ih) * D_ + d;
      FragU b1, b2;
#pragma unroll
      for (int p = 0; p < 4; ++p) {
        unsigned h0, l0, h1, l1;
        dk_split(wp[(2 * p) * D_], h0, l0);
        dk_split(wp[(2 * p + 1) * D_], h1, l1);
        b1.u[p] = (h0 >> 16) | h1;
        b2.u[p] = l0 | (l1 << 16);
      }
      if (UNIFORM) {
        s_t[ct] = __builtin_amdgcn_mfma_f32_16x16x32_bf16(a1.f, b1.f, s_t[ct], 0, 0, 0);
        s_t[ct] = __builtin_amdgcn_mfma_f32_16x16x32_bf16(a1.f, b2.f, s_t[ct], 0, 0, 0);
      } else {
        f32x4 acc = (f32x4){0.f, 0.f, 0.f, 0.f};
        acc = __builtin_amdgcn_mfma_f32_16x16x32_bf16(a1.f, b1.f, acc, 0, 0, 0);
        u_t[ct] = __builtin_amdgcn_mfma_f32_16x16x32_bf16(a1.f, b2.f, acc, 0, 0, 0);
      }
    }
    if (!UNIFORM) {
#pragma unroll
      for (int ol = 0; ol < 4; ++ol) {
        float lg[4] = {0.f, 0.f, 0.f, 0.f};
#pragma unroll
        for (int hf = 0; hf < 2; ++hf) {
          int ct = ol * 2 + hf;
          int odc = cg * 128 + ct * 16 + c;
#pragma unroll
          for (int r = 0; r < 4; ++r)
            lg[r] = fmaf(u_t[ct][r], v[(size_t)(bg * 16 + q * 4 + r) * OD_ + odc], lg[r]);
        }
#pragma unroll
        for (int r = 0; r < 4; ++r) {
#pragma unroll
          for (int m = 1; m < 16; m <<= 1) lg[r] += __shfl_xor(lg[r], m);
        }
        if (c == 0) {
#pragma unroll
          for (int r = 0; r < 4; ++r)
            ls_logit[(q * 4 + r) * O_ + cg * 4 + ol] = lg[r];
        }
      }
      __syncthreads();
      {
        int b_l = tid >> 5, o = tid & 31;
        float l = ls_logit[b_l * O_ + o];
        float mx = l;
#pragma unroll
        for (int m = 16; m >= 1; m >>= 1) mx = fmaxf(mx, __shfl_xor(mx, m));
        float e = __expf(l - mx);
        float sm = e;
#pragma unroll
        for (int m = 16; m >= 1; m >>= 1) sm += __shfl_xor(sm, m);
        ls_c[b_l * O_ + o] = e / sm;
      }
      __syncthreads();
#pragma unroll
      for (int ol = 0; ol < 4; ++ol) {
        int o = cg * 4 + ol;
        float cc[4];
#pragma unroll
        for (int r = 0; r < 4; ++r) cc[r] = ls_c[(q * 4 + r) * O_ + o];
#pragma unroll
        for (int hf = 0; hf < 2; ++hf) {
          int ct = ol * 2 + hf;
#pragma unroll
          for (int r = 0; r < 4; ++r)
            s_t[ct][r] = fmaf(cc[r], u_t[ct][r], s_t[ct][r]);
        }
      }
    }
  }

  const float scale = UNIFORM ? (1.f / 32.f) : 1.f;
#pragma unroll
  for (int ct = 0; ct < 8; ++ct) {
#pragma unroll
    for (int r = 0; r < 4; ++r) {
      partial[((size_t)ch * B_ + bg * 16 + q * 4 + r) * OD_ + cg * 128 + ct * 16 + c] =
          s_t[ct][r] * scale;
    }
  }
}

// ---- fused reduce: sum all chunks + squash + optional prev, one kernel ----
// 256 blocks x 256 threads; 4 chunk-slices per block combined via LDS.
__global__ __launch_bounds__(256) void reduce_fused(
    const float4* __restrict__ part, int cq4, const float4* __restrict__ prev,
    float4* __restrict__ out) {
  __shared__ float4 accs[4][64];
  const int lane = threadIdx.x & 63;
  const int cg = threadIdx.x >> 6;
  const int g4 = blockIdx.x * 64 + lane;  // 256*64 = 16384 outputs
  float4 s = make_float4(0.f, 0.f, 0.f, 0.f);
  const int c0 = cg * cq4;
  for (int i = 0; i < cq4; ++i) {
    float4 p = part[(size_t)(c0 + i) * 16384 + g4];
    s.x += p.x; s.y += p.y; s.z += p.z; s.w += p.w;
  }
  accs[cg][lane] = s;
  __syncthreads();
  if (cg == 0) {
    float4 a1 = accs[1][lane], a2 = accs[2][lane], a3 = accs[3][lane];
    s.x += a1.x + a2.x + a3.x;
    s.y += a1.y + a2.y + a3.y;
    s.z += a1.z + a2.z + a3.z;
    s.w += a1.w + a2.w + a3.w;
    float sq = s.x * s.x + s.y * s.y + s.z * s.z + s.w * s.w;
#pragma unroll
    for (int m = 4; m >= 1; m >>= 1) sq += __shfl_xor(sq, m, 8);
    float scale = sq / ((1.f + sq) * (sqrtf(sq) + 1e-6f));
    float4 r = make_float4(s.x * scale, s.y * scale, s.z * scale, s.w * scale);
    if (prev) {
      float4 p = prev[g4];
      r.x += p.x; r.y += p.y; r.z += p.z; r.w += p.w;
    }
    out[g4] = r;
  }
}

// single-stage reduce (fallback path)
__global__ __launch_bounds__(256) void reduce_squash(
    const float4* __restrict__ part, int chunks,
    const float4* __restrict__ prev, float4* __restrict__ out) {
  int g4 = blockIdx.x * 256 + threadIdx.x;
  float4 s = make_float4(0.f, 0.f, 0.f, 0.f);
#pragma unroll 4
  for (int ch = 0; ch < chunks; ++ch) {
    float4 p = part[(size_t)ch * 16384 + g4];
    s.x += p.x; s.y += p.y; s.z += p.z; s.w += p.w;
  }
  float sq = s.x * s.x + s.y * s.y + s.z * s.z + s.w * s.w;
#pragma unroll
  for (int m = 4; m >= 1; m >>= 1) sq += __shfl_xor(sq, m, 8);
  float scale = sq / ((1.f + sq) * (sqrtf(sq) + 1e-6f));
  float4 r = make_float4(s.x * scale, s.y * scale, s.z * scale, s.w * scale);
  if (prev) {
    float4 p = prev[g4];
    r.x += p.x; r.y += p.y; r.z += p.z; r.w += p.w;
  }
  out[g4] = r;
}

extern "C" void kernel_launch(void* const* d_in, const int* in_sizes, int n_in,
                              void* d_out, int out_size, void* d_ws,
                              size_t ws_size, hipStream_t stream) {
  const float* x = (const float*)d_in[0];
  const float* W = (const float*)d_in[1];
  float* out = (float*)d_out;

  const size_t XP_FLOATS = 4ull * 2048 * 4 * 16 * 4;       // 2,097,152
  const size_t WP_FLOATS = 2048ull * 32 * 2 * 4 * 16 * 4;  // 33,554,432

  float* v1 = (float*)d_ws;
  float* vsum = v1 + 65536;
  float* partial = vsum + 65536;

  const int chunks = 128;  // mfma_pass6 requires NC==16
  bool packed_path =
      (131072 + (size_t)chunks * 65536 + XP_FLOATS + WP_FLOATS) * 4 <= ws_size;

  if (packed_path) {
    uint4* XP = (uint4*)(partial + (size_t)chunks * 65536);
    uint4* WP = XP + XP_FLOATS / 4;
    const int NC = N_ / chunks;  // 16
    const int cq4 = chunks / 4;  // 32
    dim3 grid(chunks, 2);

    prep_all<<<8704, 256, 0, stream>>>(W, x, WP, XP);

    mfma_pass6<1><<<grid, 1024, 0, stream>>>(XP, WP, nullptr, partial, NC);
    reduce_fused<<<256, 256, 0, stream>>>((const float4*)partial, cq4, nullptr,
                                          (float4*)v1);
    mfma_pass6<0><<<grid, 1024, 0, stream>>>(XP, WP, v1, partial, NC);
    reduce_fused<<<256, 256, 0, stream>>>((const float4*)partial, cq4,
                                          (const float4*)v1, (float4*)vsum);
    mfma_pass6<0><<<grid, 1024, 0, stream>>>(XP, WP, vsum, partial, NC);
    reduce_fused<<<256, 256, 0, stream>>>((const float4*)partial, cq4, nullptr,
                                          (float4*)out);
  } else {
    int fchunks = 128;
    while (fchunks > 1 && (131072 + (size_t)fchunks * 65536) * 4 > ws_size)
      fchunks >>= 1;
    int NC = N_ / fchunks;
    dim3 grid(fchunks, 4);

    mfma_pass_fb<1><<<grid, 512, 0, stream>>>(x, W, nullptr, partial, NC);
    reduce_squash<<<64, 256, 0, stream>>>((const float4*)partial, fchunks,
                                          nullptr, (float4*)v1);
    mfma_pass_fb<0><<<grid, 512, 0, stream>>>(x, W, v1, partial, NC);
    reduce_squash<<<64, 256, 0, stream>>>((const float4*)partial, fchunks,
                                          (const float4*)v1, (float4*)vsum);
    mfma_pass_fb<0><<<grid, 512, 0, stream>>>(x, W, vsum, partial, NC);
    reduce_squash<<<64, 256, 0, stream>>>((const float4*)partial, fchunks,
                                          nullptr, (float4*)out);
  }
}